// Round 16
// baseline (337.232 us; speedup 1.0000x reference)
//
#include <hip/hip_runtime.h>
#include <hip/hip_bf16.h>

typedef __hip_bfloat16 bf16;
typedef __attribute__((ext_vector_type(4))) float f32x4;
typedef __attribute__((ext_vector_type(8))) short bf16x8;

#define MFMA16(a,b,c) __builtin_amdgcn_mfma_f32_16x16x32_bf16((a),(b),(c),0,0,0)

static __device__ inline unsigned short bfbits(float f) {
  __hip_bfloat16 h = __float2bfloat16(f);
  union { __hip_bfloat16 h; unsigned short u; } u;
  u.h = h; return u.u;
}
static __device__ inline float bf2f(unsigned short u) {
  return __uint_as_float(((unsigned int)u) << 16);
}
static __device__ inline void gld16(const void* g, void* l) {
  __builtin_amdgcn_global_load_lds((const __attribute__((address_space(1))) void*)g,
                                   (__attribute__((address_space(3))) void*)l, 16, 0, 0);
}

// ---------------- single prep kernel: 4 weight transposes + bias table + row LUTs
__global__ __launch_bounds__(256) void prep_k(const float* __restrict__ qkv_w,
                                              const float* __restrict__ proj_w,
                                              const float* __restrict__ fc1_w,
                                              const float* __restrict__ fc2_w,
                                              const float* __restrict__ rpb,
                                              bf16* __restrict__ wqkvT,
                                              bf16* __restrict__ wprojT,
                                              bf16* __restrict__ wfc1T,
                                              bf16* __restrict__ wfc2T,
                                              unsigned short* __restrict__ biasT,
                                              unsigned int* __restrict__ rowoff0,
                                              unsigned int* __restrict__ rowmap1) {
  const int b = blockIdx.x, tid = threadIdx.x;
  if (b < 768) {                      // wqkvT: [768][256], q-scale on n<256
    int idx = b * 256 + tid;
    int n = idx >> 8, k = idx & 255;
    float v = qkv_w[k * 768 + n];
    if (n < 256) v *= 0.17677669529663687f;
    wqkvT[idx] = __float2bfloat16(v);
  } else if (b < 1024) {              // wprojT: [256][256]
    int idx = (b - 768) * 256 + tid;
    int n = idx >> 8, k = idx & 255;
    wprojT[idx] = __float2bfloat16(proj_w[k * 256 + n]);
  } else if (b < 2048) {              // wfc1T: [1024][256]
    int idx = (b - 1024) * 256 + tid;
    int n = idx >> 8, k = idx & 255;
    wfc1T[idx] = __float2bfloat16(fc1_w[k * 1024 + n]);
  } else if (b < 3072) {              // wfc2T: [256][1024]
    int idx = (b - 2048) * 256 + tid;
    int n = idx >> 10, k = idx & 1023;
    wfc2T[idx] = __float2bfloat16(fc2_w[k * 256 + n]);
  } else if (b < 3110) {              // bias table [h][k][q]
    int idx = (b - 3072) * 256 + tid;
    if (idx < 9604) {
      int nn = idx / 98, mm = idx - nn * 98;   // nn=q, mm=k
      int ld = nn / 49, lrem = nn - ld * 49, lh = lrem / 7, lw = lrem - lh * 7;
      int md = mm / 49, mrem = mm - md * 49, mh = mrem / 7, mw = mrem - mh * 7;
      int rel = (ld - md + 1) * 169 + (lh - mh + 6) * 13 + (lw - mw + 6);
      #pragma unroll
      for (int h = 0; h < 8; ++h)
        biasT[h * 9604 + mm * 98 + nn] = bfbits(rpb[rel * 8 + h]);
    }
  } else {                            // row LUTs for gemm epilogues
    int row = (b - 3110) * 256 + tid;
    if (row < 50176) {
      int widx = row / 98, n = row - widx * 98;
      rowoff0[row] = (unsigned int)(widx * 25088 + n * 32);
      int zd = widx >> 6, zh = (widx >> 3) & 7, zw = widx & 7;
      int ld = n / 49, rem = n - ld * 49, lh = rem / 7, lw = rem - lh * 7;
      int d = zd * 2 + ld, h = zh * 7 + lh, w = zw * 7 + lw;
      int dsrc = (d + 1) & 15;
      int hsrc = h + 3; if (hsrc >= 56) hsrc -= 56;
      int wsrc = w + 3; if (wsrc >= 56) wsrc -= 56;
      rowmap1[row] = (unsigned int)((dsrc * 56 + hsrc) * 56 + wsrc);
    }
  }
}

// ---------------- V transpose: qkv V part [wh][98][32] -> vt [wh][32][128] (pad 0)
__global__ __launch_bounds__(256) void vtrans_k(const unsigned short* __restrict__ v,
                                                unsigned short* __restrict__ vt) {
  __shared__ unsigned short S[98 * 33];
  const unsigned short* src = v + (size_t)blockIdx.x * 3136;
  for (int i = threadIdx.x; i < 3136; i += 256) {
    int n = i >> 5, d = i & 31;
    S[n * 33 + d] = src[i];
  }
  __syncthreads();
  unsigned short* dst = vt + ((size_t)blockIdx.x << 12);
  for (int i = threadIdx.x; i < 4096; i += 256) {
    int d = i >> 7, m = i & 127;
    dst[i] = (m < 98) ? S[m * 33 + d] : (unsigned short)0;
  }
}

// ---------------- LayerNorm (one wave per token, 4 ch/lane), LN1 + roll + partition
__global__ __launch_bounds__(256) void ln_k(const float* __restrict__ x,
                                            const float* __restrict__ g,
                                            const float* __restrict__ bias,
                                            bf16* __restrict__ out) {
  const int wid = threadIdx.x >> 6, lane = threadIdx.x & 63;
  const int t = blockIdx.x * 4 + wid;   // destination row
  int widx = t / 98, n = t - widx * 98;
  int zd = widx >> 6, zh = (widx >> 3) & 7, zw = widx & 7;
  int ld = n / 49, rem = n - ld * 49, lh = rem / 7, lw = rem - lh * 7;
  int d = zd * 2 + ld, h = zh * 7 + lh, w = zw * 7 + lw;
  int dsrc = (d + 1) & 15;
  int hsrc = h + 3; if (hsrc >= 56) hsrc -= 56;
  int wsrc = w + 3; if (wsrc >= 56) wsrc -= 56;
  int src = (dsrc * 56 + hsrc) * 56 + wsrc;
  const float4 v = *(const float4*)(x + (size_t)src * 256 + lane * 4);
  float s1 = v.x + v.y + v.z + v.w;
  float s2 = v.x * v.x + v.y * v.y + v.z * v.z + v.w * v.w;
  #pragma unroll
  for (int d2 = 1; d2 < 64; d2 <<= 1) {
    s1 += __shfl_xor(s1, d2);
    s2 += __shfl_xor(s2, d2);
  }
  float mu = s1 * (1.f / 256.f);
  float var = s2 * (1.f / 256.f) - mu * mu;
  float rs = rsqrtf(var + 1e-5f);
  const float4 gv = *(const float4*)(g + lane * 4);
  const float4 bv = *(const float4*)(bias + lane * 4);
  ushort4 pk;
  pk.x = bfbits((v.x - mu) * rs * gv.x + bv.x);
  pk.y = bfbits((v.y - mu) * rs * gv.y + bv.y);
  pk.z = bfbits((v.z - mu) * rs * gv.z + bv.z);
  pk.w = bfbits((v.w - mu) * rs * gv.w + bv.w);
  *(ushort4*)((unsigned short*)out + (size_t)t * 256 + lane * 4) = pk;
}

// ---------------- GEMM (r12 structure + TPB multi-tile persistent blocks).
// Block computes TPB consecutive output tiles; double-buffer pipeline stays warm
// across tile boundaries (next tile's first stage issues before prev epilogue).
// EPI 0: qkv scatter (rmap=rowoff0). EPI 2: fast-GELU->bf16. EPI 3: +x2 residual.
template<int EPI, int TPB>
__global__ __launch_bounds__(256) void gemm_k(const bf16* __restrict__ A,
                                              const bf16* __restrict__ Bt,
                                              const float* __restrict__ bias,
                                              int N, int K, int NX, int mrow0,
                                              bf16* __restrict__ out_bf,
                                              float* __restrict__ out_f,
                                              const float* __restrict__ add_f,
                                              const unsigned int* __restrict__ rmap) {
  __shared__ bf16 As[2][128 * 32];
  __shared__ bf16 Bs[2][128 * 32];
  const int tid = threadIdx.x;
  const int wid = tid >> 6, lane = tid & 63;
  const int q8 = gridDim.x >> 3;
  const int blk = (blockIdx.x & 7) * q8 + (blockIdx.x >> 3);
  const int tile0 = blk * TPB;
  const int lrow = tid >> 2, lcol = (tid & 3) * 8;
  const int fr = lane & 15, kh = lane >> 4, kh4 = kh * 4;
  const int wm = (wid >> 1) * 64, wn = (wid & 1) * 64;
  const int nk = K >> 5;
  f32x4 zero4 = {0.f, 0.f, 0.f, 0.f};
  f32x4 acc[4][4];
  #pragma unroll
  for (int i = 0; i < 4; ++i)
    #pragma unroll
    for (int j = 0; j < 4; ++j) acc[i][j] = zero4;

  auto stage = [&](int ot, int t, int slot) {
    int tl = tile0 + ot;
    int bx = tl % NX, by = tl / NX;
    const bf16* aP = A + (size_t)(by * 128 + lrow) * K + t * 32 + lcol;
    const bf16* bP = Bt + (size_t)(bx * 128 + lrow) * K + t * 32 + lcol;
    gld16(aP, &As[slot][lrow * 32 + lcol]);
    gld16(aP + (size_t)64 * K, &As[slot][(lrow + 64) * 32 + lcol]);
    gld16(bP, &Bs[slot][lrow * 32 + lcol]);
    gld16(bP + (size_t)64 * K, &Bs[slot][(lrow + 64) * 32 + lcol]);
  };

  stage(0, 0, 0);
  int cur = 0;
  for (int ot = 0; ot < TPB; ++ot) {
    for (int t = 0; t < nk; ++t) {
      __syncthreads();               // drains vmcnt(0): buf[cur] staged; prev reads done
      int nt = t + 1, no = ot;
      if (nt == nk) { nt = 0; ++no; }
      if (no < TPB) stage(no, nt, cur ^ 1);
      const bf16* Ab = As[cur];
      const bf16* Bb = Bs[cur];
      bf16x8 af[4], bfr[4];
      #pragma unroll
      for (int i = 0; i < 4; ++i)
        af[i] = *(const bf16x8*)&Ab[(wm + i * 16 + fr) * 32 + kh * 8];
      #pragma unroll
      for (int j = 0; j < 4; ++j)
        bfr[j] = *(const bf16x8*)&Bb[(wn + j * 16 + fr) * 32 + kh * 8];
      #pragma unroll
      for (int i = 0; i < 4; ++i)
        #pragma unroll
        for (int j = 0; j < 4; ++j)
          acc[i][j] = MFMA16(af[i], bfr[j], acc[i][j]);
      cur ^= 1;
    }

    // epilogue for tile ot (registers only; next tile's first stage in flight)
    int tl = tile0 + ot;
    int row0 = (tl / NX) * 128, col0 = (tl % NX) * 128;
    #pragma unroll
    for (int i = 0; i < 4; ++i) {
      #pragma unroll
      for (int r = 0; r < 4; ++r) {
        int row = row0 + wm + i * 16 + kh4 + r;
        unsigned int rl = (EPI == 0) ? rmap[row] : 0u;
        #pragma unroll
        for (int j = 0; j < 4; ++j) {
          int col = col0 + wn + j * 16 + fr;
          float bb = bias[col];
          if (EPI == 0 && col < 256) bb *= 0.17677669529663687f;
          float v = acc[i][j][r] + bb;
          if (EPI == 0) {
            int part = col >> 8, head = (col >> 5) & 7, hd = col & 31;
            size_t off = (size_t)part * 12845056 + rl + head * 3136 + hd;
            out_bf[off] = __float2bfloat16(v);
          } else if (EPI == 2) {
            // fast tanh-GELU (|err| <~3e-3, below bf16 ulp of hh)
            float y = 0.7978845608028654f * (v + 0.044715f * v * v * v);
            float e = __expf(-2.0f * fabsf(y));
            float th = __builtin_copysignf((1.f - e) / (1.f + e), y);
            float gl = 0.5f * v * (1.f + th);
            out_bf[(size_t)row * 1024 + col] = __float2bfloat16(gl);
          } else {
            size_t ro = (size_t)(mrow0 + row);
            out_f[ro * 256 + col] = add_f[ro * 256 + col] + v;
          }
        }
      }
    }
    if (ot + 1 < TPB) {
      #pragma unroll
      for (int i = 0; i < 4; ++i)
        #pragma unroll
        for (int j = 0; j < 4; ++j) acc[i][j] = zero4;
    }
  }
}

// ---------------- proj GEMM + residual + LN2 fused (r15, unchanged).
__global__ __launch_bounds__(512) void gemm1ln_k(const bf16* __restrict__ A,
                                                 const bf16* __restrict__ Bt,
                                                 const float* __restrict__ bias,
                                                 const float* __restrict__ add_f,
                                                 const unsigned int* __restrict__ rmap,
                                                 const float* __restrict__ g2,
                                                 const float* __restrict__ b2,
                                                 float* __restrict__ x2,
                                                 bf16* __restrict__ hbuf) {
  __shared__ bf16 As[2][128 * 32];
  __shared__ bf16 Bs[2][256 * 32];
  __shared__ float red1[128][4];
  __shared__ float red2[128][4];
  const int tid = threadIdx.x;
  const int wid = tid >> 6, lane = tid & 63;
  const int tile = (blockIdx.x & 7) * 49 + (blockIdx.x >> 3);  // grid 392 = 8*49
  const int row0 = tile * 128;
  const int fr = lane & 15, kh = lane >> 4, kh4 = kh * 4;
  const int wm = (wid >> 2) * 64, wn = (wid & 3) * 64;
  f32x4 zero4 = {0.f, 0.f, 0.f, 0.f};
  f32x4 acc[4][4];
  #pragma unroll
  for (int i = 0; i < 4; ++i)
    #pragma unroll
    for (int j = 0; j < 4; ++j) acc[i][j] = zero4;

  const int srow = tid >> 2, sq = (tid & 3) * 8;
  const bf16* aP = A + (size_t)(row0 + srow) * 256 + sq;
  const bf16* bP = Bt + (size_t)srow * 256 + sq;
  const bf16* bP2 = Bt + (size_t)(srow + 128) * 256 + sq;
  bf16* asD = &As[0][srow * 32 + sq];
  bf16* bsD = &Bs[0][srow * 32 + sq];
  bf16* bsD2 = &Bs[0][(srow + 128) * 32 + sq];

  gld16(aP, asD);
  gld16(bP, bsD);
  gld16(bP2, bsD2);

  int cur = 0;
  for (int t = 0; t < 8; ++t) {
    __syncthreads();
    if (t + 1 < 8) {
      int k0 = (t + 1) * 32;
      int so = (cur ^ 1);
      gld16(aP + k0, asD + so * 4096);
      gld16(bP + k0, bsD + so * 8192);
      gld16(bP2 + k0, bsD2 + so * 8192);
    }
    const bf16* Ab = As[cur];
    const bf16* Bb = Bs[cur];
    bf16x8 af[4], bfr[4];
    #pragma unroll
    for (int i = 0; i < 4; ++i)
      af[i] = *(const bf16x8*)&Ab[(wm + i * 16 + fr) * 32 + kh * 8];
    #pragma unroll
    for (int j = 0; j < 4; ++j)
      bfr[j] = *(const bf16x8*)&Bb[(wn + j * 16 + fr) * 32 + kh * 8];
    #pragma unroll
    for (int i = 0; i < 4; ++i)
      #pragma unroll
      for (int j = 0; j < 4; ++j)
        acc[i][j] = MFMA16(af[i], bfr[j], acc[i][j]);
    cur ^= 1;
  }

  // epilogue 1: t = x + proj + bias -> x2 (scatter), keep t in acc
  #pragma unroll
  for (int i = 0; i < 4; ++i) {
    #pragma unroll
    for (int r = 0; r < 4; ++r) {
      int rowL = wm + i * 16 + kh4 + r;
      unsigned int rl = rmap[row0 + rowL];
      const float* xr = add_f + (size_t)rl * 256;
      float* x2r = x2 + (size_t)rl * 256;
      #pragma unroll
      for (int j = 0; j < 4; ++j) {
        int col = wn + j * 16 + fr;
        float t = acc[i][j][r] + bias[col] + xr[col];
        x2r[col] = t;
        acc[i][j][r] = t;
      }
    }
  }
  // epilogue 2: row sums (4 cols in-thread, 16 lanes via shuffle, 4 waves via LDS)
  #pragma unroll
  for (int i = 0; i < 4; ++i) {
    #pragma unroll
    for (int r = 0; r < 4; ++r) {
      float s1 = 0.f, s2 = 0.f;
      #pragma unroll
      for (int j = 0; j < 4; ++j) {
        float t = acc[i][j][r];
        s1 += t; s2 += t * t;
      }
      #pragma unroll
      for (int d = 1; d < 16; d <<= 1) {
        s1 += __shfl_xor(s1, d);
        s2 += __shfl_xor(s2, d);
      }
      if (fr == 0) {
        int rowL = wm + i * 16 + kh4 + r;
        red1[rowL][wid & 3] = s1;
        red2[rowL][wid & 3] = s2;
      }
    }
  }
  __syncthreads();
  // epilogue 3: LN -> hbuf (token order)
  #pragma unroll
  for (int i = 0; i < 4; ++i) {
    #pragma unroll
    for (int r = 0; r < 4; ++r) {
      int rowL = wm + i * 16 + kh4 + r;
      float s1 = red1[rowL][0] + red1[rowL][1] + red1[rowL][2] + red1[rowL][3];
      float s2 = red2[rowL][0] + red2[rowL][1] + red2[rowL][2] + red2[rowL][3];
      float mu = s1 * (1.f / 256.f);
      float rs = rsqrtf(s2 * (1.f / 256.f) - mu * mu + 1e-5f);
      unsigned int rl = rmap[row0 + rowL];
      bf16* hr = hbuf + (size_t)rl * 256;
      #pragma unroll
      for (int j = 0; j < 4; ++j) {
        int col = wn + j * 16 + fr;
        float h = (acc[i][j][r] - mu) * rs * g2[col] + b2[col];
        hr[col] = __float2bfloat16(h);
      }
    }
  }
}

// ---------------- windowed attention, SWAPPED-QK form, r11 softmax trim (unchanged).
__global__ __launch_bounds__(256, 2) void attn_k(const bf16* __restrict__ qkv,
                                                 const unsigned short* __restrict__ vt,
                                                 const unsigned short* __restrict__ bias_bf,
                                                 bf16* __restrict__ out) {
  __shared__ unsigned short Pl[112 * 128];
  __shared__ unsigned short biasS[112 * 100];
  __shared__ float invS[112];
  __shared__ unsigned char lblS[112];
  const int tid = threadIdx.x;
  const int widx = blockIdx.x >> 1, hh = blockIdx.x & 1;
  const int wid = tid >> 6, lane = tid & 63;
  const int fr = lane & 15, kh = lane >> 4, kh4 = kh * 4;
  const int tr0 = wid * 2;
  f32x4 zero4 = {0.f, 0.f, 0.f, 0.f};

  if (tid < 112) {
    unsigned char l = 255;
    if (tid < 98) {
      int zd = widx >> 6, zh = (widx >> 3) & 7, zw = widx & 7;
      int ld = tid / 49, rem = tid - ld * 49, lh = rem / 7, lw = rem - lh * 7;
      int d = zd * 2 + ld, h = zh * 7 + lh, w = zw * 7 + lw;
      int cd = (d >= 14) + (d >= 15);
      int ch = (h >= 49) + (h >= 53);
      int cw = (w >= 49) + (w >= 53);
      l = (unsigned char)(cd * 9 + ch * 3 + cw);
    }
    lblS[tid] = l;
  }
  __syncthreads();

  unsigned int lblK[7];
  #pragma unroll
  for (int mt = 0; mt < 7; ++mt)
    lblK[mt] = *(const unsigned int*)&lblS[mt * 16 + kh4];
  const bool t1v = (tr0 + 1) < 7;
  unsigned int lq0 = 0x01010101u * lblS[tr0 * 16 + fr];
  unsigned int lq1 = 0x01010101u * lblS[(t1v ? tr0 + 1 : 0) * 16 + fr];

  for (int it = 0; it < 4; ++it) {
    const int head = hh * 4 + it;
    const unsigned short* qbu = (const unsigned short*)qkv + ((size_t)widx * 8 + head) * 3136;
    const unsigned short* kbu = qbu + (size_t)12845056;
    const unsigned short* brow = bias_bf + head * 9604;
    const unsigned short* vtb = vt + (((size_t)widx * 8 + head) << 12);

    __syncthreads();
    for (int j = tid; j < 4802; j += 256) {
      int n = j / 49, m2 = (j - n * 49) * 2;
      *(unsigned int*)&biasS[n * 100 + m2] = *(const unsigned int*)(brow + n * 98 + m2);
    }
    for (int j = tid; j < 700; j += 256) {
      int n = j / 50, m2 = (j - n * 50) * 2;
      *(unsigned int*)&biasS[(98 + n) * 100 + m2] = 0xFF80FF80u;
    }

    int qr0 = tr0 * 16 + fr; if (qr0 > 97) qr0 = 97;
    int qr1 = (tr0 + 1) * 16 + fr; if (qr1 > 97) qr1 = 97;
    bf16x8 aq0 = *(const bf16x8*)(qbu + qr0 * 32 + kh * 8);
    bf16x8 aq1 = *(const bf16x8*)(qbu + qr1 * 32 + kh * 8);

    f32x4 s2[2][7];
    #pragma unroll
    for (int a = 0; a < 2; ++a)
      #pragma unroll
      for (int m = 0; m < 7; ++m) s2[a][m] = zero4;
    #pragma unroll
    for (int mt = 0; mt < 7; ++mt) {
      int krow = mt * 16 + fr; if (krow > 97) krow = 97;
      bf16x8 kf = *(const bf16x8*)(kbu + krow * 32 + kh * 8);
      s2[0][mt] = MFMA16(kf, aq0, s2[0][mt]);
      s2[1][mt] = MFMA16(kf, aq1, s2[1][mt]);
    }
    __syncthreads();

    #pragma unroll
    for (int ti = 0; ti < 2; ++ti) {
      int tr = tr0 + ti;
      if (tr < 7) {
        int q = tr * 16 + fr;
        int qc = (q < 98) ? q : 0;
        unsigned int lq = (ti == 0) ? lq0 : lq1;
        float mxa = -1e30f, mxb = -1e30f;
        #pragma unroll
        for (int mt = 0; mt < 7; ++mt) {
          unsigned int df = lblK[mt] ^ lq;
          #pragma unroll
          for (int r = 0; r < 4; ++r) {
            int k = mt * 16 + kh4 + r;
            float b = bf2f(biasS[k * 100 + qc]);
            float msk = ((df >> (8 * r)) & 255u) ? -100.f : 0.f;
            s2[ti][mt][r] = s2[ti][mt][r] + b + msk;
          }
          mxa = fmaxf(mxa, fmaxf(s2[ti][mt][0], s2[ti][mt][1]));
          mxb = fmaxf(mxb, fmaxf(s2[ti][mt][2], s2[ti][mt][3]));
        }
        float mx = fmaxf(mxa, mxb);
        mx = fmaxf(mx, __shfl_xor(mx, 16));
        mx = fmaxf(mx, __shfl_xor(mx, 32));
        float suma = 0.f, sumb = 0.f;
        #pragma unroll
        for (int mt = 0; mt < 7; ++mt) {
          float e0 = __expf(s2[ti][mt][0] - mx);
          float e1 = __expf(s2[ti][mt][1] - mx);
          float e2 = __expf(s2[ti][mt][2] - mx);
          float e3 = __expf(s2[ti][mt][3] - mx);
          s2[ti][mt][0] = e0; s2[ti][mt][1] = e1;
          s2[ti][mt][2] = e2; s2[ti][mt][3] = e3;
          suma += e0 + e1; sumb += e2 + e3;
        }
        float sum = suma + sumb;
        sum += __shfl_xor(sum, 16);
        sum += __shfl_xor(sum, 32);
        if (kh == 0) invS[q] = 1.0f / sum;
        #pragma unroll
        for (int mt = 0; mt < 7; ++mt) {
          ushort4 pk;
          pk.x = bfbits(s2[ti][mt][0]);
          pk.y = bfbits(s2[ti][mt][1]);
          pk.z = bfbits(s2[ti][mt][2]);
          pk.w = bfbits(s2[ti][mt][3]);
          *(ushort4*)&Pl[(q * 128 + mt * 16 + kh4) ^ ((q & 7) << 3)] = pk;
        }
        ushort4 zz; zz.x = zz.y = zz.z = zz.w = 0;
        *(ushort4*)&Pl[(q * 128 + 112 + kh4) ^ ((q & 7) << 3)] = zz;
      }
    }
    // no barrier: PV reads only this wave's own Pl/invS rows (in-order DS pipe)

    f32x4 o00 = zero4, o01 = zero4, o10 = zero4, o11 = zero4;
    #pragma unroll
    for (int kk = 0; kk < 4; ++kk) {
      bf16x8 vv0 = *(const bf16x8*)(vtb + fr * 128 + kk * 32 + kh * 8);
      bf16x8 vv1 = *(const bf16x8*)(vtb + (16 + fr) * 128 + kk * 32 + kh * 8);
      int prow0 = tr0 * 16 + fr;
      bf16x8 pa0 = *(const bf16x8*)&((const bf16*)Pl)[(prow0 * 128 + kk * 32 + kh * 8) ^ ((prow0 & 7) << 3)];
      o00 = MFMA16(pa0, vv0, o00);
      o01 = MFMA16(pa0, vv1, o01);
      if (t1v) {
        int prow1 = prow0 + 16;
        bf16x8 pa1 = *(const bf16x8*)&((const bf16*)Pl)[(prow1 * 128 + kk * 32 + kh * 8) ^ ((prow1 & 7) << 3)];
        o10 = MFMA16(pa1, vv0, o10);
        o11 = MFMA16(pa1, vv1, o11);
      }
    }
    #pragma unroll
    for (int r = 0; r < 4; ++r) {
      int row = tr0 * 16 + kh4 + r;
      if (row < 98) {
        float iv = invS[row];
        size_t grow = (size_t)widx * 98 + row;
        out[grow * 256 + head * 32 + fr] = __float2bfloat16(o00[r] * iv);
        out[grow * 256 + head * 32 + 16 + fr] = __float2bfloat16(o01[r] * iv);
      }
    }
    if (t1v) {
      #pragma unroll
      for (int r = 0; r < 4; ++r) {
        int row = (tr0 + 1) * 16 + kh4 + r;
        if (row < 98) {
          float iv = invS[row];
          size_t grow = (size_t)widx * 98 + row;
          out[grow * 256 + head * 32 + fr] = __float2bfloat16(o10[r] * iv);
          out[grow * 256 + head * 32 + 16 + fr] = __float2bfloat16(o11[r] * iv);
        }
      }
    }
  }
}

extern "C" void kernel_launch(void* const* d_in, const int* in_sizes, int n_in,
                              void* d_out, int out_size, void* d_ws, size_t ws_size,
                              hipStream_t stream) {
  const float* x      = (const float*)d_in[0];
  const float* g1     = (const float*)d_in[2];
  const float* b1     = (const float*)d_in[3];
  const float* qkv_w  = (const float*)d_in[4];
  const float* qkv_b  = (const float*)d_in[5];
  const float* rpb    = (const float*)d_in[6];
  const float* proj_w = (const float*)d_in[7];
  const float* proj_b = (const float*)d_in[8];
  const float* g2     = (const float*)d_in[9];
  const float* b2     = (const float*)d_in[10];
  const float* fc1_w  = (const float*)d_in[11];
  const float* fc1_b  = (const float*)d_in[12];
  const float* fc2_w  = (const float*)d_in[13];
  const float* fc2_b  = (const float*)d_in[14];
  float* outp = (float*)d_out;

  char* ws = (char*)d_ws;
  if (ws_size < (size_t)156237824) return;  // need ~149 MB scratch
  bf16*  wqkvT   = (bf16*)(ws + 0);          // 768x256
  bf16*  wprojT  = (bf16*)(ws + 393216);     // 256x256
  bf16*  wfc1T   = (bf16*)(ws + 524288);     // 1024x256
  bf16*  wfc2T   = (bf16*)(ws + 1048576);    // 256x1024
  unsigned short* bias_bf = (unsigned short*)(ws + 1572864);  // 8x9604 bf16 [h][k][q]
  unsigned int* rowmap1 = (unsigned int*)(ws + 1726528);      // 50176 u32 (lives through gemm1ln)
  float* x2      = (float*)(ws + 2097152);   // 50176x256 f32 (written by gemm1ln)
  unsigned int* rowoff0 = (unsigned int*)(ws + 2097152);      // aliases x2 head (dead before x2 written)
  unsigned short* vtb = (unsigned short*)(ws + 11931648);     // 512x8x32x128 bf16, aliases x2 tail (dead before gemm1ln)
  char*  pool    = ws + 53477376;                   // 102760448 bytes
  bf16*  xw       = (bf16*)pool;                    // 50176x256 bf16 (25690112 B)
  bf16*  qkvb     = (bf16*)(pool + 25690112);       // 3x512x8x98x32 bf16 (dead after attn)
  bf16*  attn_out = (bf16*)pool;                    // reuses xw
  bf16*  hbuf     = (bf16*)(pool + 25690112);       // LN2 out, overwrites dead qkvb
  bf16*  hh       = (bf16*)(pool + 51380224);       // 25088x1024 bf16 chunk (51380224 B)

  prep_k<<<3307, 256, 0, stream>>>(qkv_w, proj_w, fc1_w, fc2_w, rpb,
                                   wqkvT, wprojT, wfc1T, wfc2T, bias_bf,
                                   rowoff0, rowmap1);

  ln_k<<<12544, 256, 0, stream>>>(x, g1, b1, xw);
  gemm_k<0, 3><<<784, 256, 0, stream>>>(xw, wqkvT, qkv_b, 768, 256, 6, 0,
                                        qkvb, nullptr, nullptr, rowoff0);
  vtrans_k<<<4096, 256, 0, stream>>>((const unsigned short*)qkvb + (size_t)2 * 12845056, vtb);
  attn_k<<<1024, 256, 0, stream>>>(qkvb, vtb, bias_bf, attn_out);
  gemm1ln_k<<<392, 512, 0, stream>>>(attn_out, wprojT, proj_b, x, rowmap1,
                                     g2, b2, x2, hbuf);
  for (int ch = 0; ch < 2; ++ch) {
    gemm_k<2, 2><<<784, 256, 0, stream>>>(hbuf + (size_t)ch * 25088 * 256, wfc1T, fc1_b,
                                          1024, 256, 8, 0, hh, nullptr, nullptr, nullptr);
    gemm_k<3, 1><<<392, 256, 0, stream>>>(hh, wfc2T, fc2_b, 256, 1024, 2, ch * 25088,
                                          nullptr, outp, x2, nullptr);
  }
}

// Round 17
// 310.526 us; speedup vs baseline: 1.0860x; 1.0860x over previous
//
#include <hip/hip_runtime.h>
#include <hip/hip_bf16.h>

typedef __hip_bfloat16 bf16;
typedef __attribute__((ext_vector_type(4))) float f32x4;
typedef __attribute__((ext_vector_type(8))) short bf16x8;

#define MFMA16(a,b,c) __builtin_amdgcn_mfma_f32_16x16x32_bf16((a),(b),(c),0,0,0)

static __device__ inline unsigned short bfbits(float f) {
  __hip_bfloat16 h = __float2bfloat16(f);
  union { __hip_bfloat16 h; unsigned short u; } u;
  u.h = h; return u.u;
}
static __device__ inline float bf2f(unsigned short u) {
  return __uint_as_float(((unsigned int)u) << 16);
}
static __device__ inline void gld16(const void* g, void* l) {
  __builtin_amdgcn_global_load_lds((const __attribute__((address_space(1))) void*)g,
                                   (__attribute__((address_space(3))) void*)l, 16, 0, 0);
}

// ---------------- single prep kernel: 4 weight transposes + bias table + row LUTs
__global__ __launch_bounds__(256) void prep_k(const float* __restrict__ qkv_w,
                                              const float* __restrict__ proj_w,
                                              const float* __restrict__ fc1_w,
                                              const float* __restrict__ fc2_w,
                                              const float* __restrict__ rpb,
                                              bf16* __restrict__ wqkvT,
                                              bf16* __restrict__ wprojT,
                                              bf16* __restrict__ wfc1T,
                                              bf16* __restrict__ wfc2T,
                                              unsigned short* __restrict__ biasT,
                                              unsigned int* __restrict__ rowoff0,
                                              unsigned int* __restrict__ rowmap1) {
  const int b = blockIdx.x, tid = threadIdx.x;
  if (b < 768) {                      // wqkvT: [768][256], q-scale on n<256
    int idx = b * 256 + tid;
    int n = idx >> 8, k = idx & 255;
    float v = qkv_w[k * 768 + n];
    if (n < 256) v *= 0.17677669529663687f;
    wqkvT[idx] = __float2bfloat16(v);
  } else if (b < 1024) {              // wprojT: [256][256]
    int idx = (b - 768) * 256 + tid;
    int n = idx >> 8, k = idx & 255;
    wprojT[idx] = __float2bfloat16(proj_w[k * 256 + n]);
  } else if (b < 2048) {              // wfc1T: [1024][256]
    int idx = (b - 1024) * 256 + tid;
    int n = idx >> 8, k = idx & 255;
    wfc1T[idx] = __float2bfloat16(fc1_w[k * 1024 + n]);
  } else if (b < 3072) {              // wfc2T: [256][1024]
    int idx = (b - 2048) * 256 + tid;
    int n = idx >> 10, k = idx & 1023;
    wfc2T[idx] = __float2bfloat16(fc2_w[k * 256 + n]);
  } else if (b < 3110) {              // bias table [h][k][q]
    int idx = (b - 3072) * 256 + tid;
    if (idx < 9604) {
      int nn = idx / 98, mm = idx - nn * 98;   // nn=q, mm=k
      int ld = nn / 49, lrem = nn - ld * 49, lh = lrem / 7, lw = lrem - lh * 7;
      int md = mm / 49, mrem = mm - md * 49, mh = mrem / 7, mw = mrem - mh * 7;
      int rel = (ld - md + 1) * 169 + (lh - mh + 6) * 13 + (lw - mw + 6);
      #pragma unroll
      for (int h = 0; h < 8; ++h)
        biasT[h * 9604 + mm * 98 + nn] = bfbits(rpb[rel * 8 + h]);
    }
  } else {                            // row LUTs for gemm epilogues
    int row = (b - 3110) * 256 + tid;
    if (row < 50176) {
      int widx = row / 98, n = row - widx * 98;
      rowoff0[row] = (unsigned int)(widx * 25088 + n * 32);
      int zd = widx >> 6, zh = (widx >> 3) & 7, zw = widx & 7;
      int ld = n / 49, rem = n - ld * 49, lh = rem / 7, lw = rem - lh * 7;
      int d = zd * 2 + ld, h = zh * 7 + lh, w = zw * 7 + lw;
      int dsrc = (d + 1) & 15;
      int hsrc = h + 3; if (hsrc >= 56) hsrc -= 56;
      int wsrc = w + 3; if (wsrc >= 56) wsrc -= 56;
      rowmap1[row] = (unsigned int)((dsrc * 56 + hsrc) * 56 + wsrc);
    }
  }
}

// ---------------- V transpose: qkv V part [wh][98][32] -> vt [wh][32][128] (pad 0)
__global__ __launch_bounds__(256) void vtrans_k(const unsigned short* __restrict__ v,
                                                unsigned short* __restrict__ vt) {
  __shared__ unsigned short S[98 * 33];
  const unsigned short* src = v + (size_t)blockIdx.x * 3136;
  for (int i = threadIdx.x; i < 3136; i += 256) {
    int n = i >> 5, d = i & 31;
    S[n * 33 + d] = src[i];
  }
  __syncthreads();
  unsigned short* dst = vt + ((size_t)blockIdx.x << 12);
  for (int i = threadIdx.x; i < 4096; i += 256) {
    int d = i >> 7, m = i & 127;
    dst[i] = (m < 98) ? S[m * 33 + d] : (unsigned short)0;
  }
}

// ---------------- LayerNorm (one wave per token, 4 ch/lane), LN1 + roll + partition
__global__ __launch_bounds__(256) void ln_k(const float* __restrict__ x,
                                            const float* __restrict__ g,
                                            const float* __restrict__ bias,
                                            bf16* __restrict__ out) {
  const int wid = threadIdx.x >> 6, lane = threadIdx.x & 63;
  const int t = blockIdx.x * 4 + wid;   // destination row
  int widx = t / 98, n = t - widx * 98;
  int zd = widx >> 6, zh = (widx >> 3) & 7, zw = widx & 7;
  int ld = n / 49, rem = n - ld * 49, lh = rem / 7, lw = rem - lh * 7;
  int d = zd * 2 + ld, h = zh * 7 + lh, w = zw * 7 + lw;
  int dsrc = (d + 1) & 15;
  int hsrc = h + 3; if (hsrc >= 56) hsrc -= 56;
  int wsrc = w + 3; if (wsrc >= 56) wsrc -= 56;
  int src = (dsrc * 56 + hsrc) * 56 + wsrc;
  const float4 v = *(const float4*)(x + (size_t)src * 256 + lane * 4);
  float s1 = v.x + v.y + v.z + v.w;
  float s2 = v.x * v.x + v.y * v.y + v.z * v.z + v.w * v.w;
  #pragma unroll
  for (int d2 = 1; d2 < 64; d2 <<= 1) {
    s1 += __shfl_xor(s1, d2);
    s2 += __shfl_xor(s2, d2);
  }
  float mu = s1 * (1.f / 256.f);
  float var = s2 * (1.f / 256.f) - mu * mu;
  float rs = rsqrtf(var + 1e-5f);
  const float4 gv = *(const float4*)(g + lane * 4);
  const float4 bv = *(const float4*)(bias + lane * 4);
  ushort4 pk;
  pk.x = bfbits((v.x - mu) * rs * gv.x + bv.x);
  pk.y = bfbits((v.y - mu) * rs * gv.y + bv.y);
  pk.z = bfbits((v.z - mu) * rs * gv.z + bv.z);
  pk.w = bfbits((v.w - mu) * rs * gv.w + bv.w);
  *(ushort4*)((unsigned short*)out + (size_t)t * 256 + lane * 4) = pk;
}

// ---------------- GEMM (r12/r15 structure: 128x128 tile, 256 thr, 2-phase dbuf).
// EPI 0: qkv scatter (rmap=rowoff0). EPI 2: fast-GELU->bf16. EPI 3: +x2 residual.
template<int EPI>
__global__ __launch_bounds__(256) void gemm_k(const bf16* __restrict__ A,
                                              const bf16* __restrict__ Bt,
                                              const float* __restrict__ bias,
                                              int N, int K, int NX, int mrow0,
                                              bf16* __restrict__ out_bf,
                                              float* __restrict__ out_f,
                                              const float* __restrict__ add_f,
                                              const unsigned int* __restrict__ rmap) {
  __shared__ bf16 As[2][128 * 32];
  __shared__ bf16 Bs[2][128 * 32];
  const int tid = threadIdx.x;
  const int wid = tid >> 6, lane = tid & 63;
  const int q8 = gridDim.x >> 3;
  const int tile = (blockIdx.x & 7) * q8 + (blockIdx.x >> 3);
  const int bx = tile % NX, by = tile / NX;
  const int row0 = by * 128, col0 = bx * 128;
  const int lrow = tid >> 2, lcol = (tid & 3) * 8;
  const int fr = lane & 15, kh = lane >> 4, kh4 = kh * 4;
  const int wm = (wid >> 1) * 64, wn = (wid & 1) * 64;
  f32x4 zero4 = {0.f, 0.f, 0.f, 0.f};
  f32x4 acc[4][4];
  #pragma unroll
  for (int i = 0; i < 4; ++i)
    #pragma unroll
    for (int j = 0; j < 4; ++j) acc[i][j] = zero4;

  const bf16* aP = A + (size_t)(row0 + lrow) * K + lcol;
  const bf16* bP = Bt + (size_t)(col0 + lrow) * K + lcol;
  bf16* asD = &As[0][lrow * 32 + lcol];
  bf16* bsD = &Bs[0][lrow * 32 + lcol];

  const int nk = K >> 5;
  gld16(aP, asD);
  gld16(aP + (size_t)64 * K, asD + 2048);
  gld16(bP, bsD);
  gld16(bP + (size_t)64 * K, bsD + 2048);

  int cur = 0;
  for (int t = 0; t < nk; ++t) {
    __syncthreads();
    if (t + 1 < nk) {
      int k0 = (t + 1) * 32;
      bf16* aD = asD + (cur ^ 1) * 4096;
      bf16* bD = bsD + (cur ^ 1) * 4096;
      gld16(aP + k0, aD);
      gld16(aP + (size_t)64 * K + k0, aD + 2048);
      gld16(bP + k0, bD);
      gld16(bP + (size_t)64 * K + k0, bD + 2048);
    }
    const bf16* Ab = As[cur];
    const bf16* Bb = Bs[cur];
    bf16x8 af[4], bfr[4];
    #pragma unroll
    for (int i = 0; i < 4; ++i)
      af[i] = *(const bf16x8*)&Ab[(wm + i * 16 + fr) * 32 + kh * 8];
    #pragma unroll
    for (int j = 0; j < 4; ++j)
      bfr[j] = *(const bf16x8*)&Bb[(wn + j * 16 + fr) * 32 + kh * 8];
    #pragma unroll
    for (int i = 0; i < 4; ++i)
      #pragma unroll
      for (int j = 0; j < 4; ++j)
        acc[i][j] = MFMA16(af[i], bfr[j], acc[i][j]);
    cur ^= 1;
  }

  #pragma unroll
  for (int i = 0; i < 4; ++i) {
    #pragma unroll
    for (int r = 0; r < 4; ++r) {
      int row = row0 + wm + i * 16 + kh4 + r;
      unsigned int rl = (EPI == 0) ? rmap[row] : 0u;
      #pragma unroll
      for (int j = 0; j < 4; ++j) {
        int col = col0 + wn + j * 16 + fr;
        float bb = bias[col];
        if (EPI == 0 && col < 256) bb *= 0.17677669529663687f;
        float v = acc[i][j][r] + bb;
        if (EPI == 0) {
          int part = col >> 8, head = (col >> 5) & 7, hd = col & 31;
          size_t off = (size_t)part * 12845056 + rl + head * 3136 + hd;
          out_bf[off] = __float2bfloat16(v);
        } else if (EPI == 2) {
          // fast tanh-GELU (|err| <~3e-3, below bf16 ulp of hh; absmax verified r16)
          float y = 0.7978845608028654f * (v + 0.044715f * v * v * v);
          float e = __expf(-2.0f * fabsf(y));
          float th = __builtin_copysignf((1.f - e) / (1.f + e), y);
          float gl = 0.5f * v * (1.f + th);
          out_bf[(size_t)row * 1024 + col] = __float2bfloat16(gl);
        } else {
          size_t ro = (size_t)(mrow0 + row);
          out_f[ro * 256 + col] = add_f[ro * 256 + col] + v;
        }
      }
    }
  }
}

// ---------------- proj GEMM + residual + LN2 fused (r15, unchanged).
__global__ __launch_bounds__(512) void gemm1ln_k(const bf16* __restrict__ A,
                                                 const bf16* __restrict__ Bt,
                                                 const float* __restrict__ bias,
                                                 const float* __restrict__ add_f,
                                                 const unsigned int* __restrict__ rmap,
                                                 const float* __restrict__ g2,
                                                 const float* __restrict__ b2,
                                                 float* __restrict__ x2,
                                                 bf16* __restrict__ hbuf) {
  __shared__ bf16 As[2][128 * 32];
  __shared__ bf16 Bs[2][256 * 32];
  __shared__ float red1[128][4];
  __shared__ float red2[128][4];
  const int tid = threadIdx.x;
  const int wid = tid >> 6, lane = tid & 63;
  const int tile = (blockIdx.x & 7) * 49 + (blockIdx.x >> 3);  // grid 392 = 8*49
  const int row0 = tile * 128;
  const int fr = lane & 15, kh = lane >> 4, kh4 = kh * 4;
  const int wm = (wid >> 2) * 64, wn = (wid & 3) * 64;
  f32x4 zero4 = {0.f, 0.f, 0.f, 0.f};
  f32x4 acc[4][4];
  #pragma unroll
  for (int i = 0; i < 4; ++i)
    #pragma unroll
    for (int j = 0; j < 4; ++j) acc[i][j] = zero4;

  const int srow = tid >> 2, sq = (tid & 3) * 8;
  const bf16* aP = A + (size_t)(row0 + srow) * 256 + sq;
  const bf16* bP = Bt + (size_t)srow * 256 + sq;
  const bf16* bP2 = Bt + (size_t)(srow + 128) * 256 + sq;
  bf16* asD = &As[0][srow * 32 + sq];
  bf16* bsD = &Bs[0][srow * 32 + sq];
  bf16* bsD2 = &Bs[0][(srow + 128) * 32 + sq];

  gld16(aP, asD);
  gld16(bP, bsD);
  gld16(bP2, bsD2);

  int cur = 0;
  for (int t = 0; t < 8; ++t) {
    __syncthreads();
    if (t + 1 < 8) {
      int k0 = (t + 1) * 32;
      int so = (cur ^ 1);
      gld16(aP + k0, asD + so * 4096);
      gld16(bP + k0, bsD + so * 8192);
      gld16(bP2 + k0, bsD2 + so * 8192);
    }
    const bf16* Ab = As[cur];
    const bf16* Bb = Bs[cur];
    bf16x8 af[4], bfr[4];
    #pragma unroll
    for (int i = 0; i < 4; ++i)
      af[i] = *(const bf16x8*)&Ab[(wm + i * 16 + fr) * 32 + kh * 8];
    #pragma unroll
    for (int j = 0; j < 4; ++j)
      bfr[j] = *(const bf16x8*)&Bb[(wn + j * 16 + fr) * 32 + kh * 8];
    #pragma unroll
    for (int i = 0; i < 4; ++i)
      #pragma unroll
      for (int j = 0; j < 4; ++j)
        acc[i][j] = MFMA16(af[i], bfr[j], acc[i][j]);
    cur ^= 1;
  }

  // epilogue 1: t = x + proj + bias -> x2 (scatter), keep t in acc
  #pragma unroll
  for (int i = 0; i < 4; ++i) {
    #pragma unroll
    for (int r = 0; r < 4; ++r) {
      int rowL = wm + i * 16 + kh4 + r;
      unsigned int rl = rmap[row0 + rowL];
      const float* xr = add_f + (size_t)rl * 256;
      float* x2r = x2 + (size_t)rl * 256;
      #pragma unroll
      for (int j = 0; j < 4; ++j) {
        int col = wn + j * 16 + fr;
        float t = acc[i][j][r] + bias[col] + xr[col];
        x2r[col] = t;
        acc[i][j][r] = t;
      }
    }
  }
  // epilogue 2: row sums (4 cols in-thread, 16 lanes via shuffle, 4 waves via LDS)
  #pragma unroll
  for (int i = 0; i < 4; ++i) {
    #pragma unroll
    for (int r = 0; r < 4; ++r) {
      float s1 = 0.f, s2 = 0.f;
      #pragma unroll
      for (int j = 0; j < 4; ++j) {
        float t = acc[i][j][r];
        s1 += t; s2 += t * t;
      }
      #pragma unroll
      for (int d = 1; d < 16; d <<= 1) {
        s1 += __shfl_xor(s1, d);
        s2 += __shfl_xor(s2, d);
      }
      if (fr == 0) {
        int rowL = wm + i * 16 + kh4 + r;
        red1[rowL][wid & 3] = s1;
        red2[rowL][wid & 3] = s2;
      }
    }
  }
  __syncthreads();
  // epilogue 3: LN -> hbuf (token order)
  #pragma unroll
  for (int i = 0; i < 4; ++i) {
    #pragma unroll
    for (int r = 0; r < 4; ++r) {
      int rowL = wm + i * 16 + kh4 + r;
      float s1 = red1[rowL][0] + red1[rowL][1] + red1[rowL][2] + red1[rowL][3];
      float s2 = red2[rowL][0] + red2[rowL][1] + red2[rowL][2] + red2[rowL][3];
      float mu = s1 * (1.f / 256.f);
      float rs = rsqrtf(s2 * (1.f / 256.f) - mu * mu + 1e-5f);
      unsigned int rl = rmap[row0 + rowL];
      bf16* hr = hbuf + (size_t)rl * 256;
      #pragma unroll
      for (int j = 0; j < 4; ++j) {
        int col = wn + j * 16 + fr;
        float h = (acc[i][j][r] - mu) * rs * g2[col] + b2[col];
        hr[col] = __float2bfloat16(h);
      }
    }
  }
}

// ---------------- windowed attention, SWAPPED-QK form, r11 softmax trim (unchanged).
__global__ __launch_bounds__(256, 2) void attn_k(const bf16* __restrict__ qkv,
                                                 const unsigned short* __restrict__ vt,
                                                 const unsigned short* __restrict__ bias_bf,
                                                 bf16* __restrict__ out) {
  __shared__ unsigned short Pl[112 * 128];
  __shared__ unsigned short biasS[112 * 100];
  __shared__ float invS[112];
  __shared__ unsigned char lblS[112];
  const int tid = threadIdx.x;
  const int widx = blockIdx.x >> 1, hh = blockIdx.x & 1;
  const int wid = tid >> 6, lane = tid & 63;
  const int fr = lane & 15, kh = lane >> 4, kh4 = kh * 4;
  const int tr0 = wid * 2;
  f32x4 zero4 = {0.f, 0.f, 0.f, 0.f};

  if (tid < 112) {
    unsigned char l = 255;
    if (tid < 98) {
      int zd = widx >> 6, zh = (widx >> 3) & 7, zw = widx & 7;
      int ld = tid / 49, rem = tid - ld * 49, lh = rem / 7, lw = rem - lh * 7;
      int d = zd * 2 + ld, h = zh * 7 + lh, w = zw * 7 + lw;
      int cd = (d >= 14) + (d >= 15);
      int ch = (h >= 49) + (h >= 53);
      int cw = (w >= 49) + (w >= 53);
      l = (unsigned char)(cd * 9 + ch * 3 + cw);
    }
    lblS[tid] = l;
  }
  __syncthreads();

  unsigned int lblK[7];
  #pragma unroll
  for (int mt = 0; mt < 7; ++mt)
    lblK[mt] = *(const unsigned int*)&lblS[mt * 16 + kh4];
  const bool t1v = (tr0 + 1) < 7;
  unsigned int lq0 = 0x01010101u * lblS[tr0 * 16 + fr];
  unsigned int lq1 = 0x01010101u * lblS[(t1v ? tr0 + 1 : 0) * 16 + fr];

  for (int it = 0; it < 4; ++it) {
    const int head = hh * 4 + it;
    const unsigned short* qbu = (const unsigned short*)qkv + ((size_t)widx * 8 + head) * 3136;
    const unsigned short* kbu = qbu + (size_t)12845056;
    const unsigned short* brow = bias_bf + head * 9604;
    const unsigned short* vtb = vt + (((size_t)widx * 8 + head) << 12);

    __syncthreads();
    for (int j = tid; j < 4802; j += 256) {
      int n = j / 49, m2 = (j - n * 49) * 2;
      *(unsigned int*)&biasS[n * 100 + m2] = *(const unsigned int*)(brow + n * 98 + m2);
    }
    for (int j = tid; j < 700; j += 256) {
      int n = j / 50, m2 = (j - n * 50) * 2;
      *(unsigned int*)&biasS[(98 + n) * 100 + m2] = 0xFF80FF80u;
    }

    int qr0 = tr0 * 16 + fr; if (qr0 > 97) qr0 = 97;
    int qr1 = (tr0 + 1) * 16 + fr; if (qr1 > 97) qr1 = 97;
    bf16x8 aq0 = *(const bf16x8*)(qbu + qr0 * 32 + kh * 8);
    bf16x8 aq1 = *(const bf16x8*)(qbu + qr1 * 32 + kh * 8);

    f32x4 s2[2][7];
    #pragma unroll
    for (int a = 0; a < 2; ++a)
      #pragma unroll
      for (int m = 0; m < 7; ++m) s2[a][m] = zero4;
    #pragma unroll
    for (int mt = 0; mt < 7; ++mt) {
      int krow = mt * 16 + fr; if (krow > 97) krow = 97;
      bf16x8 kf = *(const bf16x8*)(kbu + krow * 32 + kh * 8);
      s2[0][mt] = MFMA16(kf, aq0, s2[0][mt]);
      s2[1][mt] = MFMA16(kf, aq1, s2[1][mt]);
    }
    __syncthreads();

    #pragma unroll
    for (int ti = 0; ti < 2; ++ti) {
      int tr = tr0 + ti;
      if (tr < 7) {
        int q = tr * 16 + fr;
        int qc = (q < 98) ? q : 0;
        unsigned int lq = (ti == 0) ? lq0 : lq1;
        float mxa = -1e30f, mxb = -1e30f;
        #pragma unroll
        for (int mt = 0; mt < 7; ++mt) {
          unsigned int df = lblK[mt] ^ lq;
          #pragma unroll
          for (int r = 0; r < 4; ++r) {
            int k = mt * 16 + kh4 + r;
            float b = bf2f(biasS[k * 100 + qc]);
            float msk = ((df >> (8 * r)) & 255u) ? -100.f : 0.f;
            s2[ti][mt][r] = s2[ti][mt][r] + b + msk;
          }
          mxa = fmaxf(mxa, fmaxf(s2[ti][mt][0], s2[ti][mt][1]));
          mxb = fmaxf(mxb, fmaxf(s2[ti][mt][2], s2[ti][mt][3]));
        }
        float mx = fmaxf(mxa, mxb);
        mx = fmaxf(mx, __shfl_xor(mx, 16));
        mx = fmaxf(mx, __shfl_xor(mx, 32));
        float suma = 0.f, sumb = 0.f;
        #pragma unroll
        for (int mt = 0; mt < 7; ++mt) {
          float e0 = __expf(s2[ti][mt][0] - mx);
          float e1 = __expf(s2[ti][mt][1] - mx);
          float e2 = __expf(s2[ti][mt][2] - mx);
          float e3 = __expf(s2[ti][mt][3] - mx);
          s2[ti][mt][0] = e0; s2[ti][mt][1] = e1;
          s2[ti][mt][2] = e2; s2[ti][mt][3] = e3;
          suma += e0 + e1; sumb += e2 + e3;
        }
        float sum = suma + sumb;
        sum += __shfl_xor(sum, 16);
        sum += __shfl_xor(sum, 32);
        if (kh == 0) invS[q] = 1.0f / sum;
        #pragma unroll
        for (int mt = 0; mt < 7; ++mt) {
          ushort4 pk;
          pk.x = bfbits(s2[ti][mt][0]);
          pk.y = bfbits(s2[ti][mt][1]);
          pk.z = bfbits(s2[ti][mt][2]);
          pk.w = bfbits(s2[ti][mt][3]);
          *(ushort4*)&Pl[(q * 128 + mt * 16 + kh4) ^ ((q & 7) << 3)] = pk;
        }
        ushort4 zz; zz.x = zz.y = zz.z = zz.w = 0;
        *(ushort4*)&Pl[(q * 128 + 112 + kh4) ^ ((q & 7) << 3)] = zz;
      }
    }
    // no barrier: PV reads only this wave's own Pl/invS rows (in-order DS pipe)

    f32x4 o00 = zero4, o01 = zero4, o10 = zero4, o11 = zero4;
    #pragma unroll
    for (int kk = 0; kk < 4; ++kk) {
      bf16x8 vv0 = *(const bf16x8*)(vtb + fr * 128 + kk * 32 + kh * 8);
      bf16x8 vv1 = *(const bf16x8*)(vtb + (16 + fr) * 128 + kk * 32 + kh * 8);
      int prow0 = tr0 * 16 + fr;
      bf16x8 pa0 = *(const bf16x8*)&((const bf16*)Pl)[(prow0 * 128 + kk * 32 + kh * 8) ^ ((prow0 & 7) << 3)];
      o00 = MFMA16(pa0, vv0, o00);
      o01 = MFMA16(pa0, vv1, o01);
      if (t1v) {
        int prow1 = prow0 + 16;
        bf16x8 pa1 = *(const bf16x8*)&((const bf16*)Pl)[(prow1 * 128 + kk * 32 + kh * 8) ^ ((prow1 & 7) << 3)];
        o10 = MFMA16(pa1, vv0, o10);
        o11 = MFMA16(pa1, vv1, o11);
      }
    }
    #pragma unroll
    for (int r = 0; r < 4; ++r) {
      int row = tr0 * 16 + kh4 + r;
      if (row < 98) {
        float iv = invS[row];
        size_t grow = (size_t)widx * 98 + row;
        out[grow * 256 + head * 32 + fr] = __float2bfloat16(o00[r] * iv);
        out[grow * 256 + head * 32 + 16 + fr] = __float2bfloat16(o01[r] * iv);
      }
    }
    if (t1v) {
      #pragma unroll
      for (int r = 0; r < 4; ++r) {
        int row = (tr0 + 1) * 16 + kh4 + r;
        if (row < 98) {
          float iv = invS[row];
          size_t grow = (size_t)widx * 98 + row;
          out[grow * 256 + head * 32 + fr] = __float2bfloat16(o10[r] * iv);
          out[grow * 256 + head * 32 + 16 + fr] = __float2bfloat16(o11[r] * iv);
        }
      }
    }
  }
}

extern "C" void kernel_launch(void* const* d_in, const int* in_sizes, int n_in,
                              void* d_out, int out_size, void* d_ws, size_t ws_size,
                              hipStream_t stream) {
  const float* x      = (const float*)d_in[0];
  const float* g1     = (const float*)d_in[2];
  const float* b1     = (const float*)d_in[3];
  const float* qkv_w  = (const float*)d_in[4];
  const float* qkv_b  = (const float*)d_in[5];
  const float* rpb    = (const float*)d_in[6];
  const float* proj_w = (const float*)d_in[7];
  const float* proj_b = (const float*)d_in[8];
  const float* g2     = (const float*)d_in[9];
  const float* b2     = (const float*)d_in[10];
  const float* fc1_w  = (const float*)d_in[11];
  const float* fc1_b  = (const float*)d_in[12];
  const float* fc2_w  = (const float*)d_in[13];
  const float* fc2_b  = (const float*)d_in[14];
  float* outp = (float*)d_out;

  char* ws = (char*)d_ws;
  if (ws_size < (size_t)156237824) return;  // need ~149 MB scratch
  bf16*  wqkvT   = (bf16*)(ws + 0);          // 768x256
  bf16*  wprojT  = (bf16*)(ws + 393216);     // 256x256
  bf16*  wfc1T   = (bf16*)(ws + 524288);     // 1024x256
  bf16*  wfc2T   = (bf16*)(ws + 1048576);    // 256x1024
  unsigned short* bias_bf = (unsigned short*)(ws + 1572864);  // 8x9604 bf16 [h][k][q]
  unsigned int* rowmap1 = (unsigned int*)(ws + 1726528);      // 50176 u32 (lives through gemm1ln)
  float* x2      = (float*)(ws + 2097152);   // 50176x256 f32 (written by gemm1ln)
  unsigned int* rowoff0 = (unsigned int*)(ws + 2097152);      // aliases x2 head (dead before x2 written)
  unsigned short* vtb = (unsigned short*)(ws + 11931648);     // 512x8x32x128 bf16, aliases x2 tail (dead before gemm1ln)
  char*  pool    = ws + 53477376;                   // 102760448 bytes
  bf16*  xw       = (bf16*)pool;                    // 50176x256 bf16 (25690112 B)
  bf16*  qkvb     = (bf16*)(pool + 25690112);       // 3x512x8x98x32 bf16 (dead after attn)
  bf16*  attn_out = (bf16*)pool;                    // reuses xw
  bf16*  hbuf     = (bf16*)(pool + 25690112);       // LN2 out, overwrites dead qkvb
  bf16*  hh       = (bf16*)(pool + 51380224);       // 25088x1024 bf16 chunk (51380224 B)

  prep_k<<<3307, 256, 0, stream>>>(qkv_w, proj_w, fc1_w, fc2_w, rpb,
                                   wqkvT, wprojT, wfc1T, wfc2T, bias_bf,
                                   rowoff0, rowmap1);

  ln_k<<<12544, 256, 0, stream>>>(x, g1, b1, xw);
  gemm_k<0><<<2352, 256, 0, stream>>>(xw, wqkvT, qkv_b, 768, 256, 6, 0,
                                      qkvb, nullptr, nullptr, rowoff0);
  vtrans_k<<<4096, 256, 0, stream>>>((const unsigned short*)qkvb + (size_t)2 * 12845056, vtb);
  attn_k<<<1024, 256, 0, stream>>>(qkvb, vtb, bias_bf, attn_out);
  gemm1ln_k<<<392, 512, 0, stream>>>(attn_out, wprojT, proj_b, x, rowmap1,
                                     g2, b2, x2, hbuf);
  for (int ch = 0; ch < 2; ++ch) {
    gemm_k<2><<<1568, 256, 0, stream>>>(hbuf + (size_t)ch * 25088 * 256, wfc1T, fc1_b,
                                        1024, 256, 8, 0, hh, nullptr, nullptr, nullptr);
    gemm_k<3><<<392, 256, 0, stream>>>(hh, wfc2T, fc2_b, 256, 1024, 2, ch * 25088,
                                       nullptr, outp, x2, nullptr);
  }
}

// Round 18
// 299.038 us; speedup vs baseline: 1.1277x; 1.0384x over previous
//
#include <hip/hip_runtime.h>
#include <hip/hip_bf16.h>

typedef __hip_bfloat16 bf16;
typedef __attribute__((ext_vector_type(4))) float f32x4;
typedef __attribute__((ext_vector_type(8))) short bf16x8;

#define MFMA16(a,b,c) __builtin_amdgcn_mfma_f32_16x16x32_bf16((a),(b),(c),0,0,0)

static __device__ inline unsigned short bfbits(float f) {
  __hip_bfloat16 h = __float2bfloat16(f);
  union { __hip_bfloat16 h; unsigned short u; } u;
  u.h = h; return u.u;
}
static __device__ inline float bf2f(unsigned short u) {
  return __uint_as_float(((unsigned int)u) << 16);
}
static __device__ inline void gld16(const void* g, void* l) {
  __builtin_amdgcn_global_load_lds((const __attribute__((address_space(1))) void*)g,
                                   (__attribute__((address_space(3))) void*)l, 16, 0, 0);
}

// ---------------- single prep kernel: 4 weight transposes + bias table + row LUTs
__global__ __launch_bounds__(256) void prep_k(const float* __restrict__ qkv_w,
                                              const float* __restrict__ proj_w,
                                              const float* __restrict__ fc1_w,
                                              const float* __restrict__ fc2_w,
                                              const float* __restrict__ rpb,
                                              bf16* __restrict__ wqkvT,
                                              bf16* __restrict__ wprojT,
                                              bf16* __restrict__ wfc1T,
                                              bf16* __restrict__ wfc2T,
                                              unsigned short* __restrict__ biasT,
                                              unsigned int* __restrict__ rowoff0,
                                              unsigned int* __restrict__ rowmap1) {
  const int b = blockIdx.x, tid = threadIdx.x;
  if (b < 768) {                      // wqkvT: [768][256], q-scale on n<256
    int idx = b * 256 + tid;
    int n = idx >> 8, k = idx & 255;
    float v = qkv_w[k * 768 + n];
    if (n < 256) v *= 0.17677669529663687f;
    wqkvT[idx] = __float2bfloat16(v);
  } else if (b < 1024) {              // wprojT: [256][256]
    int idx = (b - 768) * 256 + tid;
    int n = idx >> 8, k = idx & 255;
    wprojT[idx] = __float2bfloat16(proj_w[k * 256 + n]);
  } else if (b < 2048) {              // wfc1T: [1024][256]
    int idx = (b - 1024) * 256 + tid;
    int n = idx >> 8, k = idx & 255;
    wfc1T[idx] = __float2bfloat16(fc1_w[k * 1024 + n]);
  } else if (b < 3072) {              // wfc2T: [256][1024]
    int idx = (b - 2048) * 256 + tid;
    int n = idx >> 10, k = idx & 1023;
    wfc2T[idx] = __float2bfloat16(fc2_w[k * 256 + n]);
  } else if (b < 3110) {              // bias table [h][k][q]
    int idx = (b - 3072) * 256 + tid;
    if (idx < 9604) {
      int nn = idx / 98, mm = idx - nn * 98;   // nn=q, mm=k
      int ld = nn / 49, lrem = nn - ld * 49, lh = lrem / 7, lw = lrem - lh * 7;
      int md = mm / 49, mrem = mm - md * 49, mh = mrem / 7, mw = mrem - mh * 7;
      int rel = (ld - md + 1) * 169 + (lh - mh + 6) * 13 + (lw - mw + 6);
      #pragma unroll
      for (int h = 0; h < 8; ++h)
        biasT[h * 9604 + mm * 98 + nn] = bfbits(rpb[rel * 8 + h]);
    }
  } else {                            // row LUTs for gemm epilogues
    int row = (b - 3110) * 256 + tid;
    if (row < 50176) {
      int widx = row / 98, n = row - widx * 98;
      rowoff0[row] = (unsigned int)(widx * 25088 + n * 32);
      int zd = widx >> 6, zh = (widx >> 3) & 7, zw = widx & 7;
      int ld = n / 49, rem = n - ld * 49, lh = rem / 7, lw = rem - lh * 7;
      int d = zd * 2 + ld, h = zh * 7 + lh, w = zw * 7 + lw;
      int dsrc = (d + 1) & 15;
      int hsrc = h + 3; if (hsrc >= 56) hsrc -= 56;
      int wsrc = w + 3; if (wsrc >= 56) wsrc -= 56;
      rowmap1[row] = (unsigned int)((dsrc * 56 + hsrc) * 56 + wsrc);
    }
  }
}

// ---------------- V transpose: qkv V part [wh][98][32] -> vt [wh][32][128] (pad 0)
__global__ __launch_bounds__(256) void vtrans_k(const unsigned short* __restrict__ v,
                                                unsigned short* __restrict__ vt) {
  __shared__ unsigned short S[98 * 33];
  const unsigned short* src = v + (size_t)blockIdx.x * 3136;
  for (int i = threadIdx.x; i < 3136; i += 256) {
    int n = i >> 5, d = i & 31;
    S[n * 33 + d] = src[i];
  }
  __syncthreads();
  unsigned short* dst = vt + ((size_t)blockIdx.x << 12);
  for (int i = threadIdx.x; i < 4096; i += 256) {
    int d = i >> 7, m = i & 127;
    dst[i] = (m < 98) ? S[m * 33 + d] : (unsigned short)0;
  }
}

// ---------------- LayerNorm (one wave per token, 4 ch/lane), LN1 + roll + partition
__global__ __launch_bounds__(256) void ln_k(const float* __restrict__ x,
                                            const float* __restrict__ g,
                                            const float* __restrict__ bias,
                                            bf16* __restrict__ out) {
  const int wid = threadIdx.x >> 6, lane = threadIdx.x & 63;
  const int t = blockIdx.x * 4 + wid;   // destination row
  int widx = t / 98, n = t - widx * 98;
  int zd = widx >> 6, zh = (widx >> 3) & 7, zw = widx & 7;
  int ld = n / 49, rem = n - ld * 49, lh = rem / 7, lw = rem - lh * 7;
  int d = zd * 2 + ld, h = zh * 7 + lh, w = zw * 7 + lw;
  int dsrc = (d + 1) & 15;
  int hsrc = h + 3; if (hsrc >= 56) hsrc -= 56;
  int wsrc = w + 3; if (wsrc >= 56) wsrc -= 56;
  int src = (dsrc * 56 + hsrc) * 56 + wsrc;
  const float4 v = *(const float4*)(x + (size_t)src * 256 + lane * 4);
  float s1 = v.x + v.y + v.z + v.w;
  float s2 = v.x * v.x + v.y * v.y + v.z * v.z + v.w * v.w;
  #pragma unroll
  for (int d2 = 1; d2 < 64; d2 <<= 1) {
    s1 += __shfl_xor(s1, d2);
    s2 += __shfl_xor(s2, d2);
  }
  float mu = s1 * (1.f / 256.f);
  float var = s2 * (1.f / 256.f) - mu * mu;
  float rs = rsqrtf(var + 1e-5f);
  const float4 gv = *(const float4*)(g + lane * 4);
  const float4 bv = *(const float4*)(bias + lane * 4);
  ushort4 pk;
  pk.x = bfbits((v.x - mu) * rs * gv.x + bv.x);
  pk.y = bfbits((v.y - mu) * rs * gv.y + bv.y);
  pk.z = bfbits((v.z - mu) * rs * gv.z + bv.z);
  pk.w = bfbits((v.w - mu) * rs * gv.w + bv.w);
  *(ushort4*)((unsigned short*)out + (size_t)t * 256 + lane * 4) = pk;
}

// ---------------- GEMM (r12/r15 structure: 128x128 tile, 256 thr, 2-phase dbuf).
// EPI 0: qkv scatter (rmap=rowoff0). EPI 2: exact GELU->bf16. EPI 3: +x2 residual.
template<int EPI>
__global__ __launch_bounds__(256) void gemm_k(const bf16* __restrict__ A,
                                              const bf16* __restrict__ Bt,
                                              const float* __restrict__ bias,
                                              int N, int K, int NX, int mrow0,
                                              bf16* __restrict__ out_bf,
                                              float* __restrict__ out_f,
                                              const float* __restrict__ add_f,
                                              const unsigned int* __restrict__ rmap) {
  __shared__ bf16 As[2][128 * 32];
  __shared__ bf16 Bs[2][128 * 32];
  const int tid = threadIdx.x;
  const int wid = tid >> 6, lane = tid & 63;
  const int q8 = gridDim.x >> 3;
  const int tile = (blockIdx.x & 7) * q8 + (blockIdx.x >> 3);
  const int bx = tile % NX, by = tile / NX;
  const int row0 = by * 128, col0 = bx * 128;
  const int lrow = tid >> 2, lcol = (tid & 3) * 8;
  const int fr = lane & 15, kh = lane >> 4, kh4 = kh * 4;
  const int wm = (wid >> 1) * 64, wn = (wid & 1) * 64;
  f32x4 zero4 = {0.f, 0.f, 0.f, 0.f};
  f32x4 acc[4][4];
  #pragma unroll
  for (int i = 0; i < 4; ++i)
    #pragma unroll
    for (int j = 0; j < 4; ++j) acc[i][j] = zero4;

  const bf16* aP = A + (size_t)(row0 + lrow) * K + lcol;
  const bf16* bP = Bt + (size_t)(col0 + lrow) * K + lcol;
  bf16* asD = &As[0][lrow * 32 + lcol];
  bf16* bsD = &Bs[0][lrow * 32 + lcol];

  const int nk = K >> 5;
  gld16(aP, asD);
  gld16(aP + (size_t)64 * K, asD + 2048);
  gld16(bP, bsD);
  gld16(bP + (size_t)64 * K, bsD + 2048);

  int cur = 0;
  for (int t = 0; t < nk; ++t) {
    __syncthreads();
    if (t + 1 < nk) {
      int k0 = (t + 1) * 32;
      bf16* aD = asD + (cur ^ 1) * 4096;
      bf16* bD = bsD + (cur ^ 1) * 4096;
      gld16(aP + k0, aD);
      gld16(aP + (size_t)64 * K + k0, aD + 2048);
      gld16(bP + k0, bD);
      gld16(bP + (size_t)64 * K + k0, bD + 2048);
    }
    const bf16* Ab = As[cur];
    const bf16* Bb = Bs[cur];
    bf16x8 af[4], bfr[4];
    #pragma unroll
    for (int i = 0; i < 4; ++i)
      af[i] = *(const bf16x8*)&Ab[(wm + i * 16 + fr) * 32 + kh * 8];
    #pragma unroll
    for (int j = 0; j < 4; ++j)
      bfr[j] = *(const bf16x8*)&Bb[(wn + j * 16 + fr) * 32 + kh * 8];
    #pragma unroll
    for (int i = 0; i < 4; ++i)
      #pragma unroll
      for (int j = 0; j < 4; ++j)
        acc[i][j] = MFMA16(af[i], bfr[j], acc[i][j]);
    cur ^= 1;
  }

  #pragma unroll
  for (int i = 0; i < 4; ++i) {
    #pragma unroll
    for (int r = 0; r < 4; ++r) {
      int row = row0 + wm + i * 16 + kh4 + r;
      unsigned int rl = (EPI == 0) ? rmap[row] : 0u;
      #pragma unroll
      for (int j = 0; j < 4; ++j) {
        int col = col0 + wn + j * 16 + fr;
        float bb = bias[col];
        if (EPI == 0 && col < 256) bb *= 0.17677669529663687f;
        float v = acc[i][j][r] + bb;
        if (EPI == 0) {
          int part = col >> 8, head = (col >> 5) & 7, hd = col & 31;
          size_t off = (size_t)part * 12845056 + rl + head * 3136 + hd;
          out_bf[off] = __float2bfloat16(v);
        } else if (EPI == 2) {
          float gl = 0.5f * v * (1.0f + erff(v * 0.70710678118654752f));
          out_bf[(size_t)row * 1024 + col] = __float2bfloat16(gl);
        } else {
          size_t ro = (size_t)(mrow0 + row);
          out_f[ro * 256 + col] = add_f[ro * 256 + col] + v;
        }
      }
    }
  }
}

// ---------------- proj GEMM + residual + LN2 fused (r15, unchanged).
__global__ __launch_bounds__(512) void gemm1ln_k(const bf16* __restrict__ A,
                                                 const bf16* __restrict__ Bt,
                                                 const float* __restrict__ bias,
                                                 const float* __restrict__ add_f,
                                                 const unsigned int* __restrict__ rmap,
                                                 const float* __restrict__ g2,
                                                 const float* __restrict__ b2,
                                                 float* __restrict__ x2,
                                                 bf16* __restrict__ hbuf) {
  __shared__ bf16 As[2][128 * 32];
  __shared__ bf16 Bs[2][256 * 32];
  __shared__ float red1[128][4];
  __shared__ float red2[128][4];
  const int tid = threadIdx.x;
  const int wid = tid >> 6, lane = tid & 63;
  const int tile = (blockIdx.x & 7) * 49 + (blockIdx.x >> 3);  // grid 392 = 8*49
  const int row0 = tile * 128;
  const int fr = lane & 15, kh = lane >> 4, kh4 = kh * 4;
  const int wm = (wid >> 2) * 64, wn = (wid & 3) * 64;
  f32x4 zero4 = {0.f, 0.f, 0.f, 0.f};
  f32x4 acc[4][4];
  #pragma unroll
  for (int i = 0; i < 4; ++i)
    #pragma unroll
    for (int j = 0; j < 4; ++j) acc[i][j] = zero4;

  const int srow = tid >> 2, sq = (tid & 3) * 8;
  const bf16* aP = A + (size_t)(row0 + srow) * 256 + sq;
  const bf16* bP = Bt + (size_t)srow * 256 + sq;
  const bf16* bP2 = Bt + (size_t)(srow + 128) * 256 + sq;
  bf16* asD = &As[0][srow * 32 + sq];
  bf16* bsD = &Bs[0][srow * 32 + sq];
  bf16* bsD2 = &Bs[0][(srow + 128) * 32 + sq];

  gld16(aP, asD);
  gld16(bP, bsD);
  gld16(bP2, bsD2);

  int cur = 0;
  for (int t = 0; t < 8; ++t) {
    __syncthreads();
    if (t + 1 < 8) {
      int k0 = (t + 1) * 32;
      int so = (cur ^ 1);
      gld16(aP + k0, asD + so * 4096);
      gld16(bP + k0, bsD + so * 8192);
      gld16(bP2 + k0, bsD2 + so * 8192);
    }
    const bf16* Ab = As[cur];
    const bf16* Bb = Bs[cur];
    bf16x8 af[4], bfr[4];
    #pragma unroll
    for (int i = 0; i < 4; ++i)
      af[i] = *(const bf16x8*)&Ab[(wm + i * 16 + fr) * 32 + kh * 8];
    #pragma unroll
    for (int j = 0; j < 4; ++j)
      bfr[j] = *(const bf16x8*)&Bb[(wn + j * 16 + fr) * 32 + kh * 8];
    #pragma unroll
    for (int i = 0; i < 4; ++i)
      #pragma unroll
      for (int j = 0; j < 4; ++j)
        acc[i][j] = MFMA16(af[i], bfr[j], acc[i][j]);
    cur ^= 1;
  }

  // epilogue 1: t = x + proj + bias -> x2 (scatter), keep t in acc
  #pragma unroll
  for (int i = 0; i < 4; ++i) {
    #pragma unroll
    for (int r = 0; r < 4; ++r) {
      int rowL = wm + i * 16 + kh4 + r;
      unsigned int rl = rmap[row0 + rowL];
      const float* xr = add_f + (size_t)rl * 256;
      float* x2r = x2 + (size_t)rl * 256;
      #pragma unroll
      for (int j = 0; j < 4; ++j) {
        int col = wn + j * 16 + fr;
        float t = acc[i][j][r] + bias[col] + xr[col];
        x2r[col] = t;
        acc[i][j][r] = t;
      }
    }
  }
  // epilogue 2: row sums (4 cols in-thread, 16 lanes via shuffle, 4 waves via LDS)
  #pragma unroll
  for (int i = 0; i < 4; ++i) {
    #pragma unroll
    for (int r = 0; r < 4; ++r) {
      float s1 = 0.f, s2 = 0.f;
      #pragma unroll
      for (int j = 0; j < 4; ++j) {
        float t = acc[i][j][r];
        s1 += t; s2 += t * t;
      }
      #pragma unroll
      for (int d = 1; d < 16; d <<= 1) {
        s1 += __shfl_xor(s1, d);
        s2 += __shfl_xor(s2, d);
      }
      if (fr == 0) {
        int rowL = wm + i * 16 + kh4 + r;
        red1[rowL][wid & 3] = s1;
        red2[rowL][wid & 3] = s2;
      }
    }
  }
  __syncthreads();
  // epilogue 3: LN -> hbuf (token order)
  #pragma unroll
  for (int i = 0; i < 4; ++i) {
    #pragma unroll
    for (int r = 0; r < 4; ++r) {
      int rowL = wm + i * 16 + kh4 + r;
      float s1 = red1[rowL][0] + red1[rowL][1] + red1[rowL][2] + red1[rowL][3];
      float s2 = red2[rowL][0] + red2[rowL][1] + red2[rowL][2] + red2[rowL][3];
      float mu = s1 * (1.f / 256.f);
      float rs = rsqrtf(s2 * (1.f / 256.f) - mu * mu + 1e-5f);
      unsigned int rl = rmap[row0 + rowL];
      bf16* hr = hbuf + (size_t)rl * 256;
      #pragma unroll
      for (int j = 0; j < 4; ++j) {
        int col = wn + j * 16 + fr;
        float h = (acc[i][j][r] - mu) * rs * g2[col] + b2[col];
        hr[col] = __float2bfloat16(h);
      }
    }
  }
}

// ---------------- windowed attention, SWAPPED-QK form, r11 softmax trim (unchanged).
__global__ __launch_bounds__(256, 2) void attn_k(const bf16* __restrict__ qkv,
                                                 const unsigned short* __restrict__ vt,
                                                 const unsigned short* __restrict__ bias_bf,
                                                 bf16* __restrict__ out) {
  __shared__ unsigned short Pl[112 * 128];
  __shared__ unsigned short biasS[112 * 100];
  __shared__ float invS[112];
  __shared__ unsigned char lblS[112];
  const int tid = threadIdx.x;
  const int widx = blockIdx.x >> 1, hh = blockIdx.x & 1;
  const int wid = tid >> 6, lane = tid & 63;
  const int fr = lane & 15, kh = lane >> 4, kh4 = kh * 4;
  const int tr0 = wid * 2;
  f32x4 zero4 = {0.f, 0.f, 0.f, 0.f};

  if (tid < 112) {
    unsigned char l = 255;
    if (tid < 98) {
      int zd = widx >> 6, zh = (widx >> 3) & 7, zw = widx & 7;
      int ld = tid / 49, rem = tid - ld * 49, lh = rem / 7, lw = rem - lh * 7;
      int d = zd * 2 + ld, h = zh * 7 + lh, w = zw * 7 + lw;
      int cd = (d >= 14) + (d >= 15);
      int ch = (h >= 49) + (h >= 53);
      int cw = (w >= 49) + (w >= 53);
      l = (unsigned char)(cd * 9 + ch * 3 + cw);
    }
    lblS[tid] = l;
  }
  __syncthreads();

  unsigned int lblK[7];
  #pragma unroll
  for (int mt = 0; mt < 7; ++mt)
    lblK[mt] = *(const unsigned int*)&lblS[mt * 16 + kh4];
  const bool t1v = (tr0 + 1) < 7;
  unsigned int lq0 = 0x01010101u * lblS[tr0 * 16 + fr];
  unsigned int lq1 = 0x01010101u * lblS[(t1v ? tr0 + 1 : 0) * 16 + fr];

  for (int it = 0; it < 4; ++it) {
    const int head = hh * 4 + it;
    const unsigned short* qbu = (const unsigned short*)qkv + ((size_t)widx * 8 + head) * 3136;
    const unsigned short* kbu = qbu + (size_t)12845056;
    const unsigned short* brow = bias_bf + head * 9604;
    const unsigned short* vtb = vt + (((size_t)widx * 8 + head) << 12);

    __syncthreads();
    for (int j = tid; j < 4802; j += 256) {
      int n = j / 49, m2 = (j - n * 49) * 2;
      *(unsigned int*)&biasS[n * 100 + m2] = *(const unsigned int*)(brow + n * 98 + m2);
    }
    for (int j = tid; j < 700; j += 256) {
      int n = j / 50, m2 = (j - n * 50) * 2;
      *(unsigned int*)&biasS[(98 + n) * 100 + m2] = 0xFF80FF80u;
    }

    int qr0 = tr0 * 16 + fr; if (qr0 > 97) qr0 = 97;
    int qr1 = (tr0 + 1) * 16 + fr; if (qr1 > 97) qr1 = 97;
    bf16x8 aq0 = *(const bf16x8*)(qbu + qr0 * 32 + kh * 8);
    bf16x8 aq1 = *(const bf16x8*)(qbu + qr1 * 32 + kh * 8);

    f32x4 s2[2][7];
    #pragma unroll
    for (int a = 0; a < 2; ++a)
      #pragma unroll
      for (int m = 0; m < 7; ++m) s2[a][m] = zero4;
    #pragma unroll
    for (int mt = 0; mt < 7; ++mt) {
      int krow = mt * 16 + fr; if (krow > 97) krow = 97;
      bf16x8 kf = *(const bf16x8*)(kbu + krow * 32 + kh * 8);
      s2[0][mt] = MFMA16(kf, aq0, s2[0][mt]);
      s2[1][mt] = MFMA16(kf, aq1, s2[1][mt]);
    }
    __syncthreads();

    #pragma unroll
    for (int ti = 0; ti < 2; ++ti) {
      int tr = tr0 + ti;
      if (tr < 7) {
        int q = tr * 16 + fr;
        int qc = (q < 98) ? q : 0;
        unsigned int lq = (ti == 0) ? lq0 : lq1;
        float mxa = -1e30f, mxb = -1e30f;
        #pragma unroll
        for (int mt = 0; mt < 7; ++mt) {
          unsigned int df = lblK[mt] ^ lq;
          #pragma unroll
          for (int r = 0; r < 4; ++r) {
            int k = mt * 16 + kh4 + r;
            float b = bf2f(biasS[k * 100 + qc]);
            float msk = ((df >> (8 * r)) & 255u) ? -100.f : 0.f;
            s2[ti][mt][r] = s2[ti][mt][r] + b + msk;
          }
          mxa = fmaxf(mxa, fmaxf(s2[ti][mt][0], s2[ti][mt][1]));
          mxb = fmaxf(mxb, fmaxf(s2[ti][mt][2], s2[ti][mt][3]));
        }
        float mx = fmaxf(mxa, mxb);
        mx = fmaxf(mx, __shfl_xor(mx, 16));
        mx = fmaxf(mx, __shfl_xor(mx, 32));
        float suma = 0.f, sumb = 0.f;
        #pragma unroll
        for (int mt = 0; mt < 7; ++mt) {
          float e0 = __expf(s2[ti][mt][0] - mx);
          float e1 = __expf(s2[ti][mt][1] - mx);
          float e2 = __expf(s2[ti][mt][2] - mx);
          float e3 = __expf(s2[ti][mt][3] - mx);
          s2[ti][mt][0] = e0; s2[ti][mt][1] = e1;
          s2[ti][mt][2] = e2; s2[ti][mt][3] = e3;
          suma += e0 + e1; sumb += e2 + e3;
        }
        float sum = suma + sumb;
        sum += __shfl_xor(sum, 16);
        sum += __shfl_xor(sum, 32);
        if (kh == 0) invS[q] = 1.0f / sum;
        #pragma unroll
        for (int mt = 0; mt < 7; ++mt) {
          ushort4 pk;
          pk.x = bfbits(s2[ti][mt][0]);
          pk.y = bfbits(s2[ti][mt][1]);
          pk.z = bfbits(s2[ti][mt][2]);
          pk.w = bfbits(s2[ti][mt][3]);
          *(ushort4*)&Pl[(q * 128 + mt * 16 + kh4) ^ ((q & 7) << 3)] = pk;
        }
        ushort4 zz; zz.x = zz.y = zz.z = zz.w = 0;
        *(ushort4*)&Pl[(q * 128 + 112 + kh4) ^ ((q & 7) << 3)] = zz;
      }
    }
    // no barrier: PV reads only this wave's own Pl/invS rows (in-order DS pipe)

    f32x4 o00 = zero4, o01 = zero4, o10 = zero4, o11 = zero4;
    #pragma unroll
    for (int kk = 0; kk < 4; ++kk) {
      bf16x8 vv0 = *(const bf16x8*)(vtb + fr * 128 + kk * 32 + kh * 8);
      bf16x8 vv1 = *(const bf16x8*)(vtb + (16 + fr) * 128 + kk * 32 + kh * 8);
      int prow0 = tr0 * 16 + fr;
      bf16x8 pa0 = *(const bf16x8*)&((const bf16*)Pl)[(prow0 * 128 + kk * 32 + kh * 8) ^ ((prow0 & 7) << 3)];
      o00 = MFMA16(pa0, vv0, o00);
      o01 = MFMA16(pa0, vv1, o01);
      if (t1v) {
        int prow1 = prow0 + 16;
        bf16x8 pa1 = *(const bf16x8*)&((const bf16*)Pl)[(prow1 * 128 + kk * 32 + kh * 8) ^ ((prow1 & 7) << 3)];
        o10 = MFMA16(pa1, vv0, o10);
        o11 = MFMA16(pa1, vv1, o11);
      }
    }
    #pragma unroll
    for (int r = 0; r < 4; ++r) {
      int row = tr0 * 16 + kh4 + r;
      if (row < 98) {
        float iv = invS[row];
        size_t grow = (size_t)widx * 98 + row;
        out[grow * 256 + head * 32 + fr] = __float2bfloat16(o00[r] * iv);
        out[grow * 256 + head * 32 + 16 + fr] = __float2bfloat16(o01[r] * iv);
      }
    }
    if (t1v) {
      #pragma unroll
      for (int r = 0; r < 4; ++r) {
        int row = (tr0 + 1) * 16 + kh4 + r;
        if (row < 98) {
          float iv = invS[row];
          size_t grow = (size_t)widx * 98 + row;
          out[grow * 256 + head * 32 + fr] = __float2bfloat16(o10[r] * iv);
          out[grow * 256 + head * 32 + 16 + fr] = __float2bfloat16(o11[r] * iv);
        }
      }
    }
  }
}

extern "C" void kernel_launch(void* const* d_in, const int* in_sizes, int n_in,
                              void* d_out, int out_size, void* d_ws, size_t ws_size,
                              hipStream_t stream) {
  const float* x      = (const float*)d_in[0];
  const float* g1     = (const float*)d_in[2];
  const float* b1     = (const float*)d_in[3];
  const float* qkv_w  = (const float*)d_in[4];
  const float* qkv_b  = (const float*)d_in[5];
  const float* rpb    = (const float*)d_in[6];
  const float* proj_w = (const float*)d_in[7];
  const float* proj_b = (const float*)d_in[8];
  const float* g2     = (const float*)d_in[9];
  const float* b2     = (const float*)d_in[10];
  const float* fc1_w  = (const float*)d_in[11];
  const float* fc1_b  = (const float*)d_in[12];
  const float* fc2_w  = (const float*)d_in[13];
  const float* fc2_b  = (const float*)d_in[14];
  float* outp = (float*)d_out;

  char* ws = (char*)d_ws;
  if (ws_size < (size_t)156237824) return;  // need ~149 MB scratch
  bf16*  wqkvT   = (bf16*)(ws + 0);          // 768x256
  bf16*  wprojT  = (bf16*)(ws + 393216);     // 256x256
  bf16*  wfc1T   = (bf16*)(ws + 524288);     // 1024x256
  bf16*  wfc2T   = (bf16*)(ws + 1048576);    // 256x1024
  unsigned short* bias_bf = (unsigned short*)(ws + 1572864);  // 8x9604 bf16 [h][k][q]
  unsigned int* rowmap1 = (unsigned int*)(ws + 1726528);      // 50176 u32 (lives through gemm1ln)
  float* x2      = (float*)(ws + 2097152);   // 50176x256 f32 (written by gemm1ln)
  unsigned int* rowoff0 = (unsigned int*)(ws + 2097152);      // aliases x2 head (dead before x2 written)
  unsigned short* vtb = (unsigned short*)(ws + 11931648);     // 512x8x32x128 bf16, aliases x2 tail (dead before gemm1ln)
  char*  pool    = ws + 53477376;                   // 102760448 bytes
  bf16*  xw       = (bf16*)pool;                    // 50176x256 bf16 (25690112 B)
  bf16*  qkvb     = (bf16*)(pool + 25690112);       // 3x512x8x98x32 bf16 (dead after attn)
  bf16*  attn_out = (bf16*)pool;                    // reuses xw
  bf16*  hbuf     = (bf16*)(pool + 25690112);       // LN2 out, overwrites dead qkvb
  bf16*  hh       = (bf16*)(pool + 51380224);       // 25088x1024 bf16 chunk (51380224 B)

  prep_k<<<3307, 256, 0, stream>>>(qkv_w, proj_w, fc1_w, fc2_w, rpb,
                                   wqkvT, wprojT, wfc1T, wfc2T, bias_bf,
                                   rowoff0, rowmap1);

  ln_k<<<12544, 256, 0, stream>>>(x, g1, b1, xw);
  gemm_k<0><<<2352, 256, 0, stream>>>(xw, wqkvT, qkv_b, 768, 256, 6, 0,
                                      qkvb, nullptr, nullptr, rowoff0);
  vtrans_k<<<4096, 256, 0, stream>>>((const unsigned short*)qkvb + (size_t)2 * 12845056, vtb);
  attn_k<<<1024, 256, 0, stream>>>(qkvb, vtb, bias_bf, attn_out);
  gemm1ln_k<<<392, 512, 0, stream>>>(attn_out, wprojT, proj_b, x, rowmap1,
                                     g2, b2, x2, hbuf);
  for (int ch = 0; ch < 2; ++ch) {
    gemm_k<2><<<1568, 256, 0, stream>>>(hbuf + (size_t)ch * 25088 * 256, wfc1T, fc1_b,
                                        1024, 256, 8, 0, hh, nullptr, nullptr, nullptr);
    gemm_k<3><<<392, 256, 0, stream>>>(hh, wfc2T, fc2_b, 256, 1024, 2, ch * 25088,
                                       nullptr, outp, x2, nullptr);
  }
}